// Round 1
// baseline (1111.689 us; speedup 1.0000x reference)
//
#include <hip/hip_runtime.h>
#include <math.h>

#define N_NODES 50000
#define N_EDGES 800000
#define IN_DIM  64
#define NH      4
#define HC      256   // H*C
#define SLOPE   0.2f

// K1: v_edge[k][j] = sum_c W_e[k][j*64+c] * att_edge[j][c]   (64 x 4, k-major)
__global__ __launch_bounds__(256) void k_vedge(const float* __restrict__ W_e,
                                               const float* __restrict__ att_edge,
                                               float* __restrict__ v_edge) {
    int t = threadIdx.x;          // 256 threads: t = k*4 + j
    int k = t >> 2, j = t & 3;
    float s = 0.f;
    #pragma unroll
    for (int c = 0; c < 64; ++c)
        s += W_e[k * HC + j * 64 + c] * att_edge[j * 64 + c];
    v_edge[k * 4 + j] = s;
}

// K2: h = x @ W  (N x 256), plus a_src[n][j], a_dst[n][j] via wave reduction.
// W column t lives in 64 VGPRs per thread; x row broadcast from LDS.
__global__ __launch_bounds__(256) void k_proj(const float* __restrict__ x,
                                              const float* __restrict__ W,
                                              const float* __restrict__ att_src,
                                              const float* __restrict__ att_dst,
                                              float* __restrict__ h,
                                              float* __restrict__ a_src,
                                              float* __restrict__ a_dst) {
    __shared__ float xs[64];
    int t = threadIdx.x;
    int lane = t & 63;
    float wreg[64];
    #pragma unroll
    for (int k = 0; k < 64; ++k) wreg[k] = W[k * HC + t];
    float as = att_src[t];
    float ad = att_dst[t];
    int row0 = blockIdx.x * 64;
    int rmax = N_NODES - row0; if (rmax > 64) rmax = 64;
    for (int r = 0; r < rmax; ++r) {
        int row = row0 + r;
        __syncthreads();
        if (t < 64) xs[t] = x[row * 64 + t];
        __syncthreads();
        float acc = 0.f;
        #pragma unroll
        for (int k = 0; k < 64; ++k) acc += wreg[k] * xs[k];
        h[row * HC + t] = acc;
        float rs = acc * as;
        float rd = acc * ad;
        #pragma unroll
        for (int off = 32; off >= 1; off >>= 1) {
            rs += __shfl_xor(rs, off);
            rd += __shfl_xor(rd, off);
        }
        if (lane == 0) {
            int j = t >> 6;
            a_src[row * 4 + j] = rs;
            a_dst[row * 4 + j] = rd;
        }
    }
}

// K3: one wave per edge. a_edge dot, logit, w=exp(l); atomics for z/sumae/deg;
// scatter h[src]*w into out (unnormalized).
__global__ __launch_bounds__(256) void k_edge(const int* __restrict__ ei,
                                              const float* __restrict__ edge_attr,
                                              const float* __restrict__ v_edge,
                                              const float* __restrict__ a_src,
                                              const float* __restrict__ a_dst,
                                              const float* __restrict__ h,
                                              float* __restrict__ zacc,
                                              float* __restrict__ sumae,
                                              float* __restrict__ deg,
                                              float* __restrict__ out_unnorm) {
    int wave = (int)((blockIdx.x * 256u + threadIdx.x) >> 6);
    int lane = threadIdx.x & 63;
    if (wave >= N_EDGES) return;
    int e = wave;
    int src = ei[e];
    int dst = ei[N_EDGES + e];
    float ea = edge_attr[(size_t)e * 64 + lane];
    float4 v = ((const float4*)v_edge)[lane];   // v_edge[lane][0..3]
    float p0 = ea * v.x, p1 = ea * v.y, p2 = ea * v.z, p3 = ea * v.w;
    #pragma unroll
    for (int off = 32; off >= 1; off >>= 1) {
        p0 += __shfl_xor(p0, off);
        p1 += __shfl_xor(p1, off);
        p2 += __shfl_xor(p2, off);
        p3 += __shfl_xor(p3, off);
    }
    float ae[4] = {p0, p1, p2, p3};
    float w[4];
    #pragma unroll
    for (int j = 0; j < 4; ++j) {
        float l = a_src[src * 4 + j] + a_dst[dst * 4 + j] + ae[j];
        l = l > 0.f ? l : SLOPE * l;
        w[j] = expf(l);
    }
    if (lane < 4) {
        atomicAdd(&zacc[dst * 4 + lane], w[lane]);
        atomicAdd(&sumae[dst * 4 + lane], ae[lane]);
    }
    if (lane == 4) atomicAdd(&deg[dst], 1.f);
    #pragma unroll
    for (int j = 0; j < 4; ++j) {
        float val = h[(size_t)src * HC + j * 64 + lane] * w[j];
        atomicAdd(&out_unnorm[(size_t)dst * HC + j * 64 + lane], val);
    }
}

// K4: per-node self-loop term, divide by z, add bias. In-place on d_out.
__global__ __launch_bounds__(256) void k_final(const float* __restrict__ h,
                                               const float* __restrict__ a_src,
                                               const float* __restrict__ a_dst,
                                               const float* __restrict__ zacc,
                                               const float* __restrict__ sumae,
                                               const float* __restrict__ deg,
                                               const float* __restrict__ bias,
                                               float* __restrict__ out) {
    int n = blockIdx.x;
    int t = threadIdx.x;
    int j = t >> 6;
    float d = deg[n]; if (d < 1.f) d = 1.f;
    float l = a_src[n * 4 + j] + a_dst[n * 4 + j] + sumae[n * 4 + j] / d;
    l = l > 0.f ? l : SLOPE * l;
    float wself = expf(l);
    float denom = zacc[n * 4 + j] + wself + 1e-16f;
    size_t idx = (size_t)n * HC + t;
    out[idx] = (out[idx] + h[idx] * wself) / denom + bias[t];
}

extern "C" void kernel_launch(void* const* d_in, const int* in_sizes, int n_in,
                              void* d_out, int out_size, void* d_ws, size_t ws_size,
                              hipStream_t stream) {
    const float* x        = (const float*)d_in[0];
    const int*   ei       = (const int*)d_in[1];   // (2,E) int32
    const float* edge_attr= (const float*)d_in[2];
    const float* W        = (const float*)d_in[3];
    const float* W_e      = (const float*)d_in[4];
    const float* att_src  = (const float*)d_in[5];
    const float* att_dst  = (const float*)d_in[6];
    const float* att_edge = (const float*)d_in[7];
    const float* bias     = (const float*)d_in[8];
    float* out = (float*)d_out;
    float* ws  = (float*)d_ws;

    float* h      = ws;                            // N*256 = 12,800,000 floats
    float* zacc   = h + (size_t)N_NODES * HC;      // N*4
    float* sumae  = zacc + N_NODES * 4;            // N*4
    float* deg    = sumae + N_NODES * 4;           // N
    float* a_src  = deg + N_NODES;                 // N*4
    float* a_dst  = a_src + N_NODES * 4;           // N*4
    float* v_edge = a_dst + N_NODES * 4;           // 256

    // zero z/sumae/deg (contiguous 9N floats) and the output accumulator
    hipMemsetAsync(zacc, 0, (size_t)N_NODES * 9 * sizeof(float), stream);
    hipMemsetAsync(out, 0, (size_t)out_size * sizeof(float), stream);

    k_vedge<<<1, 256, 0, stream>>>(W_e, att_edge, v_edge);
    k_proj<<<(N_NODES + 63) / 64, 256, 0, stream>>>(x, W, att_src, att_dst, h, a_src, a_dst);
    k_edge<<<(N_EDGES + 3) / 4, 256, 0, stream>>>(ei, edge_attr, v_edge, a_src, a_dst, h,
                                                  zacc, sumae, deg, out);
    k_final<<<N_NODES, 256, 0, stream>>>(h, a_src, a_dst, zacc, sumae, deg, bias, out);
}

// Round 2
// 1049.215 us; speedup vs baseline: 1.0595x; 1.0595x over previous
//
#include <hip/hip_runtime.h>
#include <math.h>

#define N_NODES 50000
#define N_EDGES 800000
#define HC      256   // H*C
#define SLOPE   0.2f

// ---------------------------------------------------------------------------
// K1: v_edge[k][j] = sum_c W_e[k][j*64+c] * att_edge[j][c]   (64 x 4, k-major)
__global__ __launch_bounds__(256) void k_vedge(const float* __restrict__ W_e,
                                               const float* __restrict__ att_edge,
                                               float* __restrict__ v_edge) {
    int t = threadIdx.x;          // t = k*4 + j
    int k = t >> 2, j = t & 3;
    float s = 0.f;
    #pragma unroll
    for (int c = 0; c < 64; ++c)
        s += W_e[k * HC + j * 64 + c] * att_edge[j * 64 + c];
    v_edge[k * 4 + j] = s;
}

// ---------------------------------------------------------------------------
// K2: h_t = (x @ W) stored transposed per node: h_t[n][c][j]  (c=0..63, j=0..3)
// plus a_src[n][j], a_dst[n][j]. No __syncthreads: each wave broadcasts x via shfl.
// Thread t owns output column t = j*64+c  (j = wave index, c = lane).
__global__ __launch_bounds__(256) void k_proj(const float* __restrict__ x,
                                              const float* __restrict__ W,
                                              const float* __restrict__ att_src,
                                              const float* __restrict__ att_dst,
                                              float* __restrict__ h_t,
                                              float* __restrict__ a_src,
                                              float* __restrict__ a_dst) {
    int t = threadIdx.x;
    int lane = t & 63;
    int wv = t >> 6;                       // head j
    float wreg[64];
    #pragma unroll
    for (int k = 0; k < 64; ++k) wreg[k] = W[k * HC + t];
    float as = att_src[t];
    float ad = att_dst[t];
    int row0 = blockIdx.x * 64;
    int rmax = N_NODES - row0; if (rmax > 64) rmax = 64;
    for (int r = 0; r < rmax; ++r) {
        int row = row0 + r;
        float xv = x[(size_t)row * 64 + lane];
        float acc = 0.f;
        #pragma unroll
        for (int k = 0; k < 64; ++k) acc += wreg[k] * __shfl(xv, k);
        h_t[(size_t)row * HC + lane * 4 + wv] = acc;   // transposed store
        float rs = acc * as;
        float rd = acc * ad;
        #pragma unroll
        for (int off = 32; off >= 1; off >>= 1) {
            rs += __shfl_xor(rs, off);
            rd += __shfl_xor(rd, off);
        }
        if (lane == 0) {
            a_src[row * 4 + wv] = rs;
            a_dst[row * 4 + wv] = rd;
        }
    }
}

// ---------------------------------------------------------------------------
// K3a: histogram of dst
__global__ __launch_bounds__(256) void k_hist(const int* __restrict__ ei,
                                              int* __restrict__ counts) {
    int e = blockIdx.x * 256 + threadIdx.x;
    if (e < N_EDGES) atomicAdd(&counts[ei[N_EDGES + e]], 1);
}

// K3b: single-block exclusive scan of counts -> rowptr; cursor starts at rowptr.
// cnt_cur aliases counts (read-before-write per index is safe).
__global__ __launch_bounds__(256) void k_scan(int* __restrict__ cnt_cur,
                                              int* __restrict__ rowptr) {
    __shared__ int parts[256];
    int t = threadIdx.x;
    const int CH = (N_NODES + 255) / 256;   // 196
    int begin = t * CH;
    int end = begin + CH; if (end > N_NODES) end = N_NODES;
    int s = 0;
    for (int i = begin; i < end; ++i) s += cnt_cur[i];
    parts[t] = s;
    __syncthreads();
    for (int off = 1; off < 256; off <<= 1) {
        int v = (t >= off) ? parts[t - off] : 0;
        __syncthreads();
        parts[t] += v;
        __syncthreads();
    }
    int base = parts[t] - s;                // exclusive
    for (int i = begin; i < end; ++i) {
        int c = cnt_cur[i];
        rowptr[i] = base;
        cnt_cur[i] = base;                  // becomes cursor
        base += c;
    }
    if (t == 255) rowptr[N_NODES] = base;   // == N_EDGES
}

// ---------------------------------------------------------------------------
// K4: one wave per edge. Compute ae (dot edge_attr . v_edge), w = exp(leaky(logit)),
// scatter (src, w4) into dst-sorted slots; atomic sumae for the self-loop mean.
__global__ __launch_bounds__(256) void k_edge_w(const int* __restrict__ ei,
                                                const float* __restrict__ edge_attr,
                                                const float* __restrict__ v_edge,
                                                const float* __restrict__ a_src,
                                                const float* __restrict__ a_dst,
                                                float* __restrict__ sumae,
                                                int* __restrict__ cursor,
                                                float* __restrict__ sorted_w,
                                                int* __restrict__ sorted_src) {
    int wave = (int)((blockIdx.x * 256u + threadIdx.x) >> 6);
    int lane = threadIdx.x & 63;
    if (wave >= N_EDGES) return;
    int e = wave;
    int src = ei[e];
    int dst = ei[N_EDGES + e];
    float ea = edge_attr[(size_t)e * 64 + lane];
    float4 v = ((const float4*)v_edge)[lane];
    float p0 = ea * v.x, p1 = ea * v.y, p2 = ea * v.z, p3 = ea * v.w;
    #pragma unroll
    for (int off = 32; off >= 1; off >>= 1) {
        p0 += __shfl_xor(p0, off);
        p1 += __shfl_xor(p1, off);
        p2 += __shfl_xor(p2, off);
        p3 += __shfl_xor(p3, off);
    }
    int p;
    if (lane == 0) p = atomicAdd(&cursor[dst], 1);
    p = __shfl(p, 0);
    if (lane < 4) {
        float aej = lane == 0 ? p0 : (lane == 1 ? p1 : (lane == 2 ? p2 : p3));
        float l = a_src[src * 4 + lane] + a_dst[dst * 4 + lane] + aej;
        l = l > 0.f ? l : SLOPE * l;
        sorted_w[(size_t)p * 4 + lane] = __expf(l);
        atomicAdd(&sumae[dst * 4 + lane], aej);
    }
    if (lane == 0) sorted_src[p] = src;
}

// ---------------------------------------------------------------------------
// K5: one wave per node. Gather-aggregate over its CSR range, fuse self-loop,
// normalize, add bias. No atomics; out written exactly once.
__global__ __launch_bounds__(256) void k_gather(const int* __restrict__ rowptr,
                                                const int* __restrict__ sorted_src,
                                                const float* __restrict__ sorted_w,
                                                const float* __restrict__ h_t,
                                                const float* __restrict__ a_src,
                                                const float* __restrict__ a_dst,
                                                const float* __restrict__ sumae,
                                                const float* __restrict__ bias,
                                                float* __restrict__ out) {
    int wave = (int)((blockIdx.x * 256u + threadIdx.x) >> 6);
    int lane = threadIdx.x & 63;
    if (wave >= N_NODES) return;
    int n = wave;
    int r0 = rowptr[n];
    int r1 = rowptr[n + 1];
    const float4* h4 = (const float4*)h_t;      // h4[n*64 + c] = {j0,j1,j2,j3}
    const float4* w4p = (const float4*)sorted_w;
    float4 acc = make_float4(0.f, 0.f, 0.f, 0.f);
    float4 z   = make_float4(0.f, 0.f, 0.f, 0.f);
    for (int i = r0; i < r1; ++i) {
        int src = sorted_src[i];                // broadcast load
        float4 w = w4p[i];                      // broadcast, sequential
        float4 hv = h4[(size_t)src * 64 + lane];
        acc.x += hv.x * w.x; acc.y += hv.y * w.y;
        acc.z += hv.z * w.z; acc.w += hv.w * w.w;
        z.x += w.x; z.y += w.y; z.z += w.z; z.w += w.w;
    }
    // self loop: a_edge_self = sumae / max(deg,1)
    float d = (float)(r1 - r0); if (d < 1.f) d = 1.f;
    float4 sa = ((const float4*)sumae)[n];
    float4 la = ((const float4*)a_src)[n];
    float4 lb = ((const float4*)a_dst)[n];
    float l0 = la.x + lb.x + sa.x / d;
    float l1 = la.y + lb.y + sa.y / d;
    float l2 = la.z + lb.z + sa.z / d;
    float l3 = la.w + lb.w + sa.w / d;
    l0 = l0 > 0.f ? l0 : SLOPE * l0;
    l1 = l1 > 0.f ? l1 : SLOPE * l1;
    l2 = l2 > 0.f ? l2 : SLOPE * l2;
    l3 = l3 > 0.f ? l3 : SLOPE * l3;
    float w0 = __expf(l0), w1 = __expf(l1), w2 = __expf(l2), w3 = __expf(l3);
    float4 hn = h4[(size_t)n * 64 + lane];
    acc.x += hn.x * w0; z.x += w0;
    acc.y += hn.y * w1; z.y += w1;
    acc.z += hn.z * w2; z.z += w2;
    acc.w += hn.w * w3; z.w += w3;
    size_t ob = (size_t)n * HC + lane;
    out[ob]       = acc.x / (z.x + 1e-16f) + bias[lane];
    out[ob + 64]  = acc.y / (z.y + 1e-16f) + bias[64 + lane];
    out[ob + 128] = acc.z / (z.z + 1e-16f) + bias[128 + lane];
    out[ob + 192] = acc.w / (z.w + 1e-16f) + bias[192 + lane];
}

// ---------------------------------------------------------------------------
extern "C" void kernel_launch(void* const* d_in, const int* in_sizes, int n_in,
                              void* d_out, int out_size, void* d_ws, size_t ws_size,
                              hipStream_t stream) {
    const float* x        = (const float*)d_in[0];
    const int*   ei       = (const int*)d_in[1];   // (2,E) int32
    const float* edge_attr= (const float*)d_in[2];
    const float* W        = (const float*)d_in[3];
    const float* W_e      = (const float*)d_in[4];
    const float* att_src  = (const float*)d_in[5];
    const float* att_dst  = (const float*)d_in[6];
    const float* att_edge = (const float*)d_in[7];
    const float* bias     = (const float*)d_in[8];
    float* out = (float*)d_out;

    // workspace layout
    float* h_t        = (float*)d_ws;                          // N*256
    float* a_src      = h_t + (size_t)N_NODES * HC;            // N*4
    float* a_dst      = a_src + N_NODES * 4;                   // N*4
    float* v_edge     = a_dst + N_NODES * 4;                   // 256
    float* sorted_w   = v_edge + 256;                          // E*4
    int*   sorted_src = (int*)(sorted_w + (size_t)N_EDGES * 4);// E
    int*   rowptr     = sorted_src + N_EDGES;                  // N+1
    float* sumae      = (float*)(rowptr + N_NODES + 1);        // N*4   (zeroed)
    int*   cnt_cur    = (int*)(sumae + N_NODES * 4);           // N     (zeroed; counts->cursor)

    // zero sumae + counts in one contiguous memset (N*5 words)
    hipMemsetAsync(sumae, 0, (size_t)N_NODES * 5 * sizeof(float), stream);

    k_vedge<<<1, 256, 0, stream>>>(W_e, att_edge, v_edge);
    k_proj<<<(N_NODES + 63) / 64, 256, 0, stream>>>(x, W, att_src, att_dst,
                                                    h_t, a_src, a_dst);
    k_hist<<<(N_EDGES + 255) / 256, 256, 0, stream>>>(ei, cnt_cur);
    k_scan<<<1, 256, 0, stream>>>(cnt_cur, rowptr);
    k_edge_w<<<(N_EDGES + 3) / 4, 256, 0, stream>>>(ei, edge_attr, v_edge,
                                                    a_src, a_dst, sumae,
                                                    cnt_cur, sorted_w, sorted_src);
    k_gather<<<(N_NODES + 3) / 4, 256, 0, stream>>>(rowptr, sorted_src, sorted_w,
                                                    h_t, a_src, a_dst, sumae,
                                                    bias, out);
}

// Round 3
// 849.720 us; speedup vs baseline: 1.3083x; 1.2348x over previous
//
#include <hip/hip_runtime.h>
#include <hip/hip_bf16.h>
#include <math.h>

#define N_NODES 50000
#define N_EDGES 800000
#define HC      256   // H*C
#define SLOPE   0.2f

// ---------------------------------------------------------------------------
// K1: v_t[j][k] = sum_c W_e[k][j*64+c] * att_edge[j][c]   (j-major 4 x 64)
__global__ __launch_bounds__(256) void k_vedge(const float* __restrict__ W_e,
                                               const float* __restrict__ att_edge,
                                               float* __restrict__ v_t) {
    int t = threadIdx.x;          // t = k*4 + j
    int k = t >> 2, j = t & 3;
    float s = 0.f;
    #pragma unroll
    for (int c = 0; c < 64; ++c)
        s += W_e[k * HC + j * 64 + c] * att_edge[j * 64 + c];
    v_t[j * 64 + k] = s;
}

// ---------------------------------------------------------------------------
// K2: h = x @ W, stored packed bf16 h_bf[n][c][j] (ushort idx n*256 + c*4 + j);
// plus a_src[n][j], a_dst[n][j]. Thread t = j*64 + c (j = wave, c = lane).
__global__ __launch_bounds__(256) void k_proj(const float* __restrict__ x,
                                              const float* __restrict__ W,
                                              const float* __restrict__ att_src,
                                              const float* __restrict__ att_dst,
                                              unsigned short* __restrict__ h_bf,
                                              float* __restrict__ a_src,
                                              float* __restrict__ a_dst) {
    int t = threadIdx.x;
    int lane = t & 63;
    int wv = t >> 6;                       // head j
    float wreg[64];
    #pragma unroll
    for (int k = 0; k < 64; ++k) wreg[k] = W[k * HC + t];
    float as = att_src[t];
    float ad = att_dst[t];
    int row0 = blockIdx.x * 64;
    int rmax = N_NODES - row0; if (rmax > 64) rmax = 64;
    for (int r = 0; r < rmax; ++r) {
        int row = row0 + r;
        float xv = x[(size_t)row * 64 + lane];
        float acc = 0.f;
        #pragma unroll
        for (int k = 0; k < 64; ++k) acc += wreg[k] * __shfl(xv, k);
        __hip_bfloat16 hb = __float2bfloat16(acc);
        h_bf[(size_t)row * 256 + lane * 4 + wv] = *(unsigned short*)&hb;
        float rs = acc * as;
        float rd = acc * ad;
        #pragma unroll
        for (int off = 32; off >= 1; off >>= 1) {
            rs += __shfl_xor(rs, off);
            rd += __shfl_xor(rd, off);
        }
        if (lane == 0) {
            a_src[row * 4 + wv] = rs;
            a_dst[row * 4 + wv] = rd;
        }
    }
}

// ---------------------------------------------------------------------------
// K3a: histogram of dst
__global__ __launch_bounds__(256) void k_hist(const int* __restrict__ ei,
                                              int* __restrict__ counts) {
    int e = blockIdx.x * 256 + threadIdx.x;
    if (e < N_EDGES) atomicAdd(&counts[ei[N_EDGES + e]], 1);
}

// K3b: single-block (1024 thr) exclusive scan counts -> rowptr; cursor init.
__global__ __launch_bounds__(1024) void k_scan(int* __restrict__ cnt_cur,
                                               int* __restrict__ rowptr) {
    int t = threadIdx.x;                    // 0..1023
    const int CH = (N_NODES + 1023) / 1024; // 49
    int begin = t * CH;
    int end = begin + CH; if (end > N_NODES) end = N_NODES;
    if (begin > N_NODES) begin = N_NODES;
    int s = 0;
    for (int i = begin; i < end; ++i) s += cnt_cur[i];
    int lane = t & 63, wv = t >> 6;
    int v = s;
    #pragma unroll
    for (int off = 1; off < 64; off <<= 1) {
        int u = __shfl_up(v, off);
        if (lane >= off) v += u;
    }
    __shared__ int wbase[16];
    if (lane == 63) wbase[wv] = v;
    __syncthreads();
    if (t == 0) {
        int run = 0;
        #pragma unroll
        for (int w2 = 0; w2 < 16; ++w2) { int c = wbase[w2]; wbase[w2] = run; run += c; }
    }
    __syncthreads();
    int base = wbase[wv] + (v - s);         // exclusive prefix of this chunk
    for (int i = begin; i < end; ++i) {
        int c = cnt_cur[i];
        rowptr[i] = base;
        cnt_cur[i] = base;                  // cursor init
        base += c;
    }
    if (t == 1023) rowptr[N_NODES] = base;  // == N_EDGES
}

// ---------------------------------------------------------------------------
// K4: streaming edge pass. Each wave handles 4 edges/iter with float4 loads.
// Computes ae[4] = edge_attr[e] . v_t, scatters (src, a_src[src]+ae) into
// dst-sorted slots; atomic sumae (raw ae) for the self-loop mean.
__global__ __launch_bounds__(256) void k_edge(const int* __restrict__ ei,
                                              const float* __restrict__ edge_attr,
                                              const float* __restrict__ v_t,
                                              const float* __restrict__ a_src,
                                              float* __restrict__ sumae,
                                              int* __restrict__ cursor,
                                              float4* __restrict__ sorted_pl,
                                              int* __restrict__ sorted_src) {
    int t = threadIdx.x;
    int lane = t & 63;
    int sub = lane & 15;                    // 16 lanes per edge
    int eq = lane >> 4;                     // edge index within quad
    // preload v rows for this sub (fixed across grid-stride loop)
    float4 v0 = ((const float4*)(v_t +   0))[sub];
    float4 v1 = ((const float4*)(v_t +  64))[sub];
    float4 v2 = ((const float4*)(v_t + 128))[sub];
    float4 v3 = ((const float4*)(v_t + 192))[sub];
    int wave_id = blockIdx.x * 4 + (t >> 6);
    int nwaves = gridDim.x * 4;
    const float4* ea4 = (const float4*)edge_attr;
    for (int g = wave_id; g < N_EDGES / 4; g += nwaves) {
        int e = g * 4 + eq;
        float4 ea = ea4[(size_t)e * 16 + sub];
        float p0 = ea.x * v0.x + ea.y * v0.y + ea.z * v0.z + ea.w * v0.w;
        float p1 = ea.x * v1.x + ea.y * v1.y + ea.z * v1.z + ea.w * v1.w;
        float p2 = ea.x * v2.x + ea.y * v2.y + ea.z * v2.z + ea.w * v2.w;
        float p3 = ea.x * v3.x + ea.y * v3.y + ea.z * v3.z + ea.w * v3.w;
        #pragma unroll
        for (int off = 1; off < 16; off <<= 1) {
            p0 += __shfl_xor(p0, off);
            p1 += __shfl_xor(p1, off);
            p2 += __shfl_xor(p2, off);
            p3 += __shfl_xor(p3, off);
        }
        if (sub < 4) {
            int dst = ei[N_EDGES + e];
            float aej = sub == 0 ? p0 : (sub == 1 ? p1 : (sub == 2 ? p2 : p3));
            atomicAdd(&sumae[dst * 4 + sub], aej);
            if (sub == 0) {
                int src = ei[e];
                int p = atomicAdd(&cursor[dst], 1);
                float4 asv = ((const float4*)a_src)[src];
                sorted_pl[p] = make_float4(p0 + asv.x, p1 + asv.y,
                                           p2 + asv.z, p3 + asv.w);
                sorted_src[p] = src;
            }
        }
    }
}

// ---------------------------------------------------------------------------
// K5: one wave per node. Gather bf16 h, compute softmax weights from partial
// logits, fuse self-loop, normalize, bias. No atomics; out written once.
__global__ __launch_bounds__(256) void k_gather(const int* __restrict__ rowptr,
                                                const int* __restrict__ sorted_src,
                                                const float4* __restrict__ sorted_pl,
                                                const unsigned short* __restrict__ h_bf,
                                                const float* __restrict__ a_src,
                                                const float* __restrict__ a_dst,
                                                const float* __restrict__ sumae,
                                                const float* __restrict__ bias,
                                                float* __restrict__ out) {
    int wave = (int)((blockIdx.x * 256u + threadIdx.x) >> 6);
    int lane = threadIdx.x & 63;
    if (wave >= N_NODES) return;
    int n = wave;
    int r0 = rowptr[n];
    int r1 = rowptr[n + 1];
    float4 ad = ((const float4*)a_dst)[n];
    const uint2* h2 = (const uint2*)h_bf;       // h2[n*64 + c] = 4 bf16 heads
    float4 acc = make_float4(0.f, 0.f, 0.f, 0.f);
    float4 z   = make_float4(0.f, 0.f, 0.f, 0.f);
    for (int i = r0; i < r1; ++i) {
        int src = sorted_src[i];                // broadcast
        float4 pl = sorted_pl[i];               // broadcast
        float l0 = pl.x + ad.x, l1 = pl.y + ad.y;
        float l2 = pl.z + ad.z, l3 = pl.w + ad.w;
        l0 = fmaxf(l0, SLOPE * l0); l1 = fmaxf(l1, SLOPE * l1);
        l2 = fmaxf(l2, SLOPE * l2); l3 = fmaxf(l3, SLOPE * l3);
        float w0 = __expf(l0), w1 = __expf(l1), w2 = __expf(l2), w3 = __expf(l3);
        uint2 hv = h2[(size_t)src * 64 + lane];
        float h0 = __uint_as_float(hv.x << 16);
        float h1 = __uint_as_float(hv.x & 0xffff0000u);
        float h2f = __uint_as_float(hv.y << 16);
        float h3 = __uint_as_float(hv.y & 0xffff0000u);
        acc.x += h0 * w0; acc.y += h1 * w1; acc.z += h2f * w2; acc.w += h3 * w3;
        z.x += w0; z.y += w1; z.z += w2; z.w += w3;
    }
    // self loop: a_edge_self = sumae / max(deg,1)
    float d = (float)(r1 - r0); if (d < 1.f) d = 1.f;
    float rdeg = 1.f / d;
    float4 sa = ((const float4*)sumae)[n];
    float4 la = ((const float4*)a_src)[n];
    float l0 = la.x + ad.x + sa.x * rdeg;
    float l1 = la.y + ad.y + sa.y * rdeg;
    float l2 = la.z + ad.z + sa.z * rdeg;
    float l3 = la.w + ad.w + sa.w * rdeg;
    l0 = fmaxf(l0, SLOPE * l0); l1 = fmaxf(l1, SLOPE * l1);
    l2 = fmaxf(l2, SLOPE * l2); l3 = fmaxf(l3, SLOPE * l3);
    float w0 = __expf(l0), w1 = __expf(l1), w2 = __expf(l2), w3 = __expf(l3);
    uint2 hv = h2[(size_t)n * 64 + lane];
    float h0 = __uint_as_float(hv.x << 16);
    float h1 = __uint_as_float(hv.x & 0xffff0000u);
    float h2f = __uint_as_float(hv.y << 16);
    float h3 = __uint_as_float(hv.y & 0xffff0000u);
    acc.x += h0 * w0; z.x += w0;
    acc.y += h1 * w1; z.y += w1;
    acc.z += h2f * w2; z.z += w2;
    acc.w += h3 * w3; z.w += w3;
    size_t ob = (size_t)n * HC + lane;
    out[ob]       = acc.x / (z.x + 1e-16f) + bias[lane];
    out[ob + 64]  = acc.y / (z.y + 1e-16f) + bias[64 + lane];
    out[ob + 128] = acc.z / (z.z + 1e-16f) + bias[128 + lane];
    out[ob + 192] = acc.w / (z.w + 1e-16f) + bias[192 + lane];
}

// ---------------------------------------------------------------------------
extern "C" void kernel_launch(void* const* d_in, const int* in_sizes, int n_in,
                              void* d_out, int out_size, void* d_ws, size_t ws_size,
                              hipStream_t stream) {
    const float* x        = (const float*)d_in[0];
    const int*   ei       = (const int*)d_in[1];   // (2,E) int32
    const float* edge_attr= (const float*)d_in[2];
    const float* W        = (const float*)d_in[3];
    const float* W_e      = (const float*)d_in[4];
    const float* att_src  = (const float*)d_in[5];
    const float* att_dst  = (const float*)d_in[6];
    const float* att_edge = (const float*)d_in[7];
    const float* bias     = (const float*)d_in[8];
    float* out = (float*)d_out;

    // workspace layout
    unsigned short* h_bf  = (unsigned short*)d_ws;             // N*256 bf16 = 25.6 MB
    float* a_src      = (float*)(h_bf + (size_t)N_NODES * 256);// N*4
    float* a_dst      = a_src + N_NODES * 4;                   // N*4
    float* v_t        = a_dst + N_NODES * 4;                   // 256
    float4* sorted_pl = (float4*)(v_t + 256);                  // E float4
    int*   sorted_src = (int*)(sorted_pl + N_EDGES);           // E
    int*   rowptr     = sorted_src + N_EDGES;                  // N+1
    float* sumae      = (float*)(rowptr + N_NODES + 1);        // N*4  (zeroed)
    int*   cnt_cur    = (int*)(sumae + N_NODES * 4);           // N    (zeroed)

    // zero sumae + counts in one contiguous memset (N*5 words)
    hipMemsetAsync(sumae, 0, (size_t)N_NODES * 5 * sizeof(float), stream);

    k_vedge<<<1, 256, 0, stream>>>(W_e, att_edge, v_t);
    k_proj<<<(N_NODES + 63) / 64, 256, 0, stream>>>(x, W, att_src, att_dst,
                                                    h_bf, a_src, a_dst);
    k_hist<<<(N_EDGES + 255) / 256, 256, 0, stream>>>(ei, cnt_cur);
    k_scan<<<1, 1024, 0, stream>>>(cnt_cur, rowptr);
    k_edge<<<2048, 256, 0, stream>>>(ei, edge_attr, v_t, a_src,
                                     sumae, cnt_cur, sorted_pl, sorted_src);
    k_gather<<<(N_NODES + 3) / 4, 256, 0, stream>>>(rowptr, sorted_src, sorted_pl,
                                                    h_bf, a_src, a_dst, sumae,
                                                    bias, out);
}

// Round 4
// 612.977 us; speedup vs baseline: 1.8136x; 1.3862x over previous
//
#include <hip/hip_runtime.h>
#include <hip/hip_bf16.h>
#include <math.h>

#define N_NODES 50000
#define N_EDGES 800000
#define HC      256   // H*C
#define SLOPE   0.2f

typedef __bf16 bf16x8 __attribute__((ext_vector_type(8)));
typedef float  f32x4  __attribute__((ext_vector_type(4)));

__device__ __forceinline__ unsigned short f2bf(float f) {
    unsigned u = __float_as_uint(f);
    unsigned r = (u + 0x7fffu + ((u >> 16) & 1u)) >> 16;
    return (unsigned short)r;
}
__device__ __forceinline__ float bf2f(unsigned short s) {
    return __uint_as_float(((unsigned)s) << 16);
}

// ---------------------------------------------------------------------------
// K1: v_t[j][k] = sum_c W_e[k][j*64+c] * att_edge[j][c]   (j-major 4 x 64)
__global__ __launch_bounds__(256) void k_vedge(const float* __restrict__ W_e,
                                               const float* __restrict__ att_edge,
                                               float* __restrict__ v_t) {
    int t = threadIdx.x;          // t = k*4 + j
    int k = t >> 2, j = t & 3;
    float s = 0.f;
    #pragma unroll
    for (int c = 0; c < 64; ++c)
        s += W_e[k * HC + j * 64 + c] * att_edge[j * 64 + c];
    v_t[j * 64 + k] = s;
}

// ---------------------------------------------------------------------------
// K2: h = x @ W via split-bf16 MFMA (hi*hi + hi*lo + lo*hi ~= fp32 exact).
// Block = 4 waves = 64 rows x 256 cols; wave w owns cols [w*64, w*64+64).
// Epilogue: h packed bf16 [n][c][j] staged via LDS -> coalesced dwordx4;
// a_src/a_dst fused from fp32 accumulators (16-lane shfl reduction).
__global__ __launch_bounds__(256) void k_proj(const float* __restrict__ x,
                                              const float* __restrict__ W,
                                              const float* __restrict__ att_src,
                                              const float* __restrict__ att_dst,
                                              unsigned short* __restrict__ h_bf,
                                              float* __restrict__ a_src,
                                              float* __restrict__ a_dst) {
    __shared__ unsigned short hs[64 * 256];   // 32 KB, mirrors global layout
    int t = threadIdx.x;
    int lane = t & 63;
    int w = t >> 6;                 // wave == head j
    int l15 = lane & 15;
    int quad = lane >> 4;
    int row0 = blockIdx.x * 64;

    // ---- B fragments: W[k][w*64+ct*16+l15], k = ks*32+quad*8+j ----
    bf16x8 bh[8], bl[8];            // frag index = ct*2 + ks
    #pragma unroll
    for (int ct = 0; ct < 4; ++ct) {
        #pragma unroll
        for (int ks = 0; ks < 2; ++ks) {
            bf16x8 h8, l8;
            #pragma unroll
            for (int j = 0; j < 8; ++j) {
                float f = W[(ks * 32 + quad * 8 + j) * 256 + w * 64 + ct * 16 + l15];
                __bf16 hi = (__bf16)f;
                h8[j] = hi;
                l8[j] = (__bf16)(f - (float)hi);
            }
            bh[ct * 2 + ks] = h8;
            bl[ct * 2 + ks] = l8;
        }
    }
    float att_s[4], att_d[4];
    #pragma unroll
    for (int ct = 0; ct < 4; ++ct) {
        att_s[ct] = att_src[w * 64 + ct * 16 + l15];
        att_d[ct] = att_dst[w * 64 + ct * 16 + l15];
    }

    #pragma unroll
    for (int rt = 0; rt < 4; ++rt) {
        int row_a = row0 + rt * 16 + l15;
        if (row_a >= N_NODES) row_a = N_NODES - 1;   // dup-load, store guarded
        bf16x8 ah[2], al[2];
        #pragma unroll
        for (int ks = 0; ks < 2; ++ks) {
            const float* xp = x + (size_t)row_a * 64 + ks * 32 + quad * 8;
            float4 x0 = ((const float4*)xp)[0];
            float4 x1 = ((const float4*)xp)[1];
            float xf[8] = {x0.x, x0.y, x0.z, x0.w, x1.x, x1.y, x1.z, x1.w};
            bf16x8 h8, l8;
            #pragma unroll
            for (int j = 0; j < 8; ++j) {
                __bf16 hi = (__bf16)xf[j];
                h8[j] = hi;
                l8[j] = (__bf16)(xf[j] - (float)hi);
            }
            ah[ks] = h8;
            al[ks] = l8;
        }
        f32x4 acc[4];
        #pragma unroll
        for (int ct = 0; ct < 4; ++ct) {
            f32x4 a = {0.f, 0.f, 0.f, 0.f};
            a = __builtin_amdgcn_mfma_f32_16x16x32_bf16(ah[0], bh[ct*2+0], a, 0, 0, 0);
            a = __builtin_amdgcn_mfma_f32_16x16x32_bf16(ah[1], bh[ct*2+1], a, 0, 0, 0);
            a = __builtin_amdgcn_mfma_f32_16x16x32_bf16(ah[0], bl[ct*2+0], a, 0, 0, 0);
            a = __builtin_amdgcn_mfma_f32_16x16x32_bf16(ah[1], bl[ct*2+1], a, 0, 0, 0);
            a = __builtin_amdgcn_mfma_f32_16x16x32_bf16(al[0], bh[ct*2+0], a, 0, 0, 0);
            a = __builtin_amdgcn_mfma_f32_16x16x32_bf16(al[1], bh[ct*2+1], a, 0, 0, 0);
            acc[ct] = a;
        }
        // stage h tile into LDS (bf16, global layout [r][c*4+w])
        #pragma unroll
        for (int ct = 0; ct < 4; ++ct) {
            #pragma unroll
            for (int reg = 0; reg < 4; ++reg) {
                int r = rt * 16 + quad * 4 + reg;
                hs[r * 256 + (ct * 16 + l15) * 4 + w] = f2bf(acc[ct][reg]);
            }
        }
        // fused a_src / a_dst
        #pragma unroll
        for (int reg = 0; reg < 4; ++reg) {
            float ps = 0.f, pd = 0.f;
            #pragma unroll
            for (int ct = 0; ct < 4; ++ct) {
                ps += acc[ct][reg] * att_s[ct];
                pd += acc[ct][reg] * att_d[ct];
            }
            #pragma unroll
            for (int off = 1; off < 16; off <<= 1) {
                ps += __shfl_xor(ps, off);
                pd += __shfl_xor(pd, off);
            }
            int row = row0 + rt * 16 + quad * 4 + reg;
            if (l15 == 0 && row < N_NODES) {
                a_src[row * 4 + w] = ps;
                a_dst[row * 4 + w] = pd;
            }
        }
    }
    __syncthreads();
    // cooperative coalesced store: 64 rows x 512 B = 2048 uint4
    const uint4* ls = (const uint4*)hs;
    uint4* gd = (uint4*)h_bf;
    #pragma unroll
    for (int i = 0; i < 8; ++i) {
        int g = i * 256 + t;
        int rl = g >> 5;                       // 32 uint4 per row
        if (row0 + rl < N_NODES)
            gd[(size_t)row0 * 32 + g] = ls[g];
    }
}

// ---------------------------------------------------------------------------
// K3a: histogram of dst
__global__ __launch_bounds__(256) void k_hist(const int* __restrict__ ei,
                                              int* __restrict__ counts) {
    int e = blockIdx.x * 256 + threadIdx.x;
    if (e < N_EDGES) atomicAdd(&counts[ei[N_EDGES + e]], 1);
}

// K3b: single-block (1024 thr) exclusive scan counts -> rowptr; cursor init.
__global__ __launch_bounds__(1024) void k_scan(int* __restrict__ cnt_cur,
                                               int* __restrict__ rowptr) {
    int t = threadIdx.x;                    // 0..1023
    const int CH = (N_NODES + 1023) / 1024; // 49
    int begin = t * CH;
    int end = begin + CH; if (end > N_NODES) end = N_NODES;
    if (begin > N_NODES) begin = N_NODES;
    int s = 0;
    for (int i = begin; i < end; ++i) s += cnt_cur[i];
    int lane = t & 63, wv = t >> 6;
    int v = s;
    #pragma unroll
    for (int off = 1; off < 64; off <<= 1) {
        int u = __shfl_up(v, off);
        if (lane >= off) v += u;
    }
    __shared__ int wbase[16];
    if (lane == 63) wbase[wv] = v;
    __syncthreads();
    if (t == 0) {
        int run = 0;
        #pragma unroll
        for (int w2 = 0; w2 < 16; ++w2) { int c = wbase[w2]; wbase[w2] = run; run += c; }
    }
    __syncthreads();
    int base = wbase[wv] + (v - s);         // exclusive prefix of this chunk
    for (int i = begin; i < end; ++i) {
        int c = cnt_cur[i];
        rowptr[i] = base;
        cnt_cur[i] = base;                  // cursor init
        base += c;
    }
    if (t == 1023) rowptr[N_NODES] = base;  // == N_EDGES
}

// ---------------------------------------------------------------------------
// K4: streaming edge pass. Each wave handles 4 edges/iter with float4 loads.
// Computes ae[4] = edge_attr[e] . v_t, scatters (src, a_src[src]+ae) into
// dst-sorted slots; atomic sumae (raw ae) for the self-loop mean.
__global__ __launch_bounds__(256) void k_edge(const int* __restrict__ ei,
                                              const float* __restrict__ edge_attr,
                                              const float* __restrict__ v_t,
                                              const float* __restrict__ a_src,
                                              float* __restrict__ sumae,
                                              int* __restrict__ cursor,
                                              float4* __restrict__ sorted_pl,
                                              int* __restrict__ sorted_src) {
    int t = threadIdx.x;
    int lane = t & 63;
    int sub = lane & 15;                    // 16 lanes per edge
    int eq = lane >> 4;                     // edge index within quad
    float4 v0 = ((const float4*)(v_t +   0))[sub];
    float4 v1 = ((const float4*)(v_t +  64))[sub];
    float4 v2 = ((const float4*)(v_t + 128))[sub];
    float4 v3 = ((const float4*)(v_t + 192))[sub];
    int wave_id = blockIdx.x * 4 + (t >> 6);
    int nwaves = gridDim.x * 4;
    const float4* ea4 = (const float4*)edge_attr;
    for (int g = wave_id; g < N_EDGES / 4; g += nwaves) {
        int e = g * 4 + eq;
        float4 ea = ea4[(size_t)e * 16 + sub];
        float p0 = ea.x * v0.x + ea.y * v0.y + ea.z * v0.z + ea.w * v0.w;
        float p1 = ea.x * v1.x + ea.y * v1.y + ea.z * v1.z + ea.w * v1.w;
        float p2 = ea.x * v2.x + ea.y * v2.y + ea.z * v2.z + ea.w * v2.w;
        float p3 = ea.x * v3.x + ea.y * v3.y + ea.z * v3.z + ea.w * v3.w;
        #pragma unroll
        for (int off = 1; off < 16; off <<= 1) {
            p0 += __shfl_xor(p0, off);
            p1 += __shfl_xor(p1, off);
            p2 += __shfl_xor(p2, off);
            p3 += __shfl_xor(p3, off);
        }
        if (sub < 4) {
            int dst = ei[N_EDGES + e];
            float aej = sub == 0 ? p0 : (sub == 1 ? p1 : (sub == 2 ? p2 : p3));
            atomicAdd(&sumae[dst * 4 + sub], aej);
            if (sub == 0) {
                int src = ei[e];
                int p = atomicAdd(&cursor[dst], 1);
                float4 asv = ((const float4*)a_src)[src];
                sorted_pl[p] = make_float4(p0 + asv.x, p1 + asv.y,
                                           p2 + asv.z, p3 + asv.w);
                sorted_src[p] = src;
            }
        }
    }
}

// ---------------------------------------------------------------------------
// K5: one wave per node. Lane-parallel preload of up to 64 (src, pl) pairs +
// lane-parallel exp; shfl-broadcast accumulate loop (h-gather addresses all
// available up front -> high MLP). Self-loop fused; out written once.
__global__ __launch_bounds__(256) void k_gather(const int* __restrict__ rowptr,
                                                const int* __restrict__ sorted_src,
                                                const float4* __restrict__ sorted_pl,
                                                const unsigned short* __restrict__ h_bf,
                                                const float* __restrict__ a_src,
                                                const float* __restrict__ a_dst,
                                                const float* __restrict__ sumae,
                                                const float* __restrict__ bias,
                                                float* __restrict__ out) {
    int wave = (int)((blockIdx.x * 256u + threadIdx.x) >> 6);
    int lane = threadIdx.x & 63;
    if (wave >= N_NODES) return;
    int n = wave;
    int r0 = rowptr[n];
    int r1 = rowptr[n + 1];
    float4 ad = ((const float4*)a_dst)[n];
    const uint2* h2 = (const uint2*)h_bf;       // h2[n*64 + c] = 4 bf16 heads
    float a0 = 0.f, a1 = 0.f, a2 = 0.f, a3 = 0.f;
    float z0 = 0.f, z1 = 0.f, z2 = 0.f, z3 = 0.f;
    for (int base = r0; base < r1; base += 64) {
        int cnt = r1 - base; if (cnt > 64) cnt = 64;
        int idx = base + (lane < cnt ? lane : 0);
        int msrc = sorted_src[idx];             // coalesced
        float4 pl = sorted_pl[idx];             // coalesced
        float l0 = pl.x + ad.x, l1 = pl.y + ad.y;
        float l2 = pl.z + ad.z, l3 = pl.w + ad.w;
        l0 = fmaxf(l0, SLOPE * l0); l1 = fmaxf(l1, SLOPE * l1);
        l2 = fmaxf(l2, SLOPE * l2); l3 = fmaxf(l3, SLOPE * l3);
        float mw0 = __expf(l0), mw1 = __expf(l1);
        float mw2 = __expf(l2), mw3 = __expf(l3);
        #pragma unroll 8
        for (int j = 0; j < cnt; ++j) {
            int src = __shfl(msrc, j);
            float e0 = __shfl(mw0, j), e1 = __shfl(mw1, j);
            float e2 = __shfl(mw2, j), e3 = __shfl(mw3, j);
            uint2 hv = h2[(size_t)src * 64 + lane];
            float h0 = __uint_as_float(hv.x << 16);
            float h1 = __uint_as_float(hv.x & 0xffff0000u);
            float h2f = __uint_as_float(hv.y << 16);
            float h3 = __uint_as_float(hv.y & 0xffff0000u);
            a0 += h0 * e0; a1 += h1 * e1; a2 += h2f * e2; a3 += h3 * e3;
            z0 += e0; z1 += e1; z2 += e2; z3 += e3;
        }
    }
    // self loop: a_edge_self = sumae / max(deg,1)
    float d = (float)(r1 - r0); if (d < 1.f) d = 1.f;
    float rdeg = 1.f / d;
    float4 sa = ((const float4*)sumae)[n];
    float4 la = ((const float4*)a_src)[n];
    float l0 = la.x + ad.x + sa.x * rdeg;
    float l1 = la.y + ad.y + sa.y * rdeg;
    float l2 = la.z + ad.z + sa.z * rdeg;
    float l3 = la.w + ad.w + sa.w * rdeg;
    l0 = fmaxf(l0, SLOPE * l0); l1 = fmaxf(l1, SLOPE * l1);
    l2 = fmaxf(l2, SLOPE * l2); l3 = fmaxf(l3, SLOPE * l3);
    float w0 = __expf(l0), w1 = __expf(l1), w2 = __expf(l2), w3 = __expf(l3);
    uint2 hv = h2[(size_t)n * 64 + lane];
    float h0 = __uint_as_float(hv.x << 16);
    float h1 = __uint_as_float(hv.x & 0xffff0000u);
    float h2f = __uint_as_float(hv.y << 16);
    float h3 = __uint_as_float(hv.y & 0xffff0000u);
    a0 += h0 * w0; z0 += w0;
    a1 += h1 * w1; z1 += w1;
    a2 += h2f * w2; z2 += w2;
    a3 += h3 * w3; z3 += w3;
    size_t ob = (size_t)n * HC + lane;
    out[ob]       = a0 / (z0 + 1e-16f) + bias[lane];
    out[ob + 64]  = a1 / (z1 + 1e-16f) + bias[64 + lane];
    out[ob + 128] = a2 / (z2 + 1e-16f) + bias[128 + lane];
    out[ob + 192] = a3 / (z3 + 1e-16f) + bias[192 + lane];
}

// ---------------------------------------------------------------------------
extern "C" void kernel_launch(void* const* d_in, const int* in_sizes, int n_in,
                              void* d_out, int out_size, void* d_ws, size_t ws_size,
                              hipStream_t stream) {
    const float* x        = (const float*)d_in[0];
    const int*   ei       = (const int*)d_in[1];   // (2,E) int32
    const float* edge_attr= (const float*)d_in[2];
    const float* W        = (const float*)d_in[3];
    const float* W_e      = (const float*)d_in[4];
    const float* att_src  = (const float*)d_in[5];
    const float* att_dst  = (const float*)d_in[6];
    const float* att_edge = (const float*)d_in[7];
    const float* bias     = (const float*)d_in[8];
    float* out = (float*)d_out;

    // workspace layout
    unsigned short* h_bf  = (unsigned short*)d_ws;             // N*256 bf16 = 25.6 MB
    float* a_src      = (float*)(h_bf + (size_t)N_NODES * 256);// N*4
    float* a_dst      = a_src + N_NODES * 4;                   // N*4
    float* v_t        = a_dst + N_NODES * 4;                   // 256
    float4* sorted_pl = (float4*)(v_t + 256);                  // E float4
    int*   sorted_src = (int*)(sorted_pl + N_EDGES);           // E
    int*   rowptr     = sorted_src + N_EDGES;                  // N+1
    float* sumae      = (float*)(rowptr + N_NODES + 1);        // N*4  (zeroed)
    int*   cnt_cur    = (int*)(sumae + N_NODES * 4);           // N    (zeroed)

    // zero sumae + counts in one contiguous memset (N*5 words)
    hipMemsetAsync(sumae, 0, (size_t)N_NODES * 5 * sizeof(float), stream);

    k_vedge<<<1, 256, 0, stream>>>(W_e, att_edge, v_t);
    k_proj<<<(N_NODES + 63) / 64, 256, 0, stream>>>(x, W, att_src, att_dst,
                                                    h_bf, a_src, a_dst);
    k_hist<<<(N_EDGES + 255) / 256, 256, 0, stream>>>(ei, cnt_cur);
    k_scan<<<1, 1024, 0, stream>>>(cnt_cur, rowptr);
    k_edge<<<2048, 256, 0, stream>>>(ei, edge_attr, v_t, a_src,
                                     sumae, cnt_cur, sorted_pl, sorted_src);
    k_gather<<<(N_NODES + 3) / 4, 256, 0, stream>>>(rowptr, sorted_src, sorted_pl,
                                                    h_bf, a_src, a_dst, sumae,
                                                    bias, out);
}

// Round 5
// 514.217 us; speedup vs baseline: 2.1619x; 1.1921x over previous
//
#include <hip/hip_runtime.h>
#include <hip/hip_bf16.h>
#include <math.h>

#define N_NODES 50000
#define N_EDGES 800000
#define HC      256   // H*C
#define SLOPE   0.2f

typedef __bf16 bf16x8 __attribute__((ext_vector_type(8)));
typedef float  f32x4  __attribute__((ext_vector_type(4)));

__device__ __forceinline__ unsigned short f2bf(float f) {
    unsigned u = __float_as_uint(f);
    unsigned r = (u + 0x7fffu + ((u >> 16) & 1u)) >> 16;
    return (unsigned short)r;
}

// ---------------------------------------------------------------------------
// K1: v_t[j][k] = sum_c W_e[k][j*64+c] * att_edge[j][c]   (j-major 4 x 64)
__global__ __launch_bounds__(256) void k_vedge(const float* __restrict__ W_e,
                                               const float* __restrict__ att_edge,
                                               float* __restrict__ v_t) {
    int t = threadIdx.x;          // t = k*4 + j
    int k = t >> 2, j = t & 3;
    float s = 0.f;
    #pragma unroll
    for (int c = 0; c < 64; ++c)
        s += W_e[k * HC + j * 64 + c] * att_edge[j * 64 + c];
    v_t[j * 64 + k] = s;
}

// ---------------------------------------------------------------------------
// K2: h = x @ W via split-bf16 MFMA (hi*hi + hi*lo + lo*hi ~= fp32 exact).
// Block = 4 waves = 64 rows x 256 cols; wave w owns cols [w*64, w*64+64).
__global__ __launch_bounds__(256) void k_proj(const float* __restrict__ x,
                                              const float* __restrict__ W,
                                              const float* __restrict__ att_src,
                                              const float* __restrict__ att_dst,
                                              unsigned short* __restrict__ h_bf,
                                              float* __restrict__ a_src,
                                              float* __restrict__ a_dst) {
    __shared__ unsigned short hs[64 * 256];   // 32 KB, mirrors global layout
    int t = threadIdx.x;
    int lane = t & 63;
    int w = t >> 6;                 // wave == head j
    int l15 = lane & 15;
    int quad = lane >> 4;
    int row0 = blockIdx.x * 64;

    bf16x8 bh[8], bl[8];            // frag index = ct*2 + ks
    #pragma unroll
    for (int ct = 0; ct < 4; ++ct) {
        #pragma unroll
        for (int ks = 0; ks < 2; ++ks) {
            bf16x8 h8, l8;
            #pragma unroll
            for (int j = 0; j < 8; ++j) {
                float f = W[(ks * 32 + quad * 8 + j) * 256 + w * 64 + ct * 16 + l15];
                __bf16 hi = (__bf16)f;
                h8[j] = hi;
                l8[j] = (__bf16)(f - (float)hi);
            }
            bh[ct * 2 + ks] = h8;
            bl[ct * 2 + ks] = l8;
        }
    }
    float att_s[4], att_d[4];
    #pragma unroll
    for (int ct = 0; ct < 4; ++ct) {
        att_s[ct] = att_src[w * 64 + ct * 16 + l15];
        att_d[ct] = att_dst[w * 64 + ct * 16 + l15];
    }

    #pragma unroll
    for (int rt = 0; rt < 4; ++rt) {
        int row_a = row0 + rt * 16 + l15;
        if (row_a >= N_NODES) row_a = N_NODES - 1;   // dup-load, store guarded
        bf16x8 ah[2], al[2];
        #pragma unroll
        for (int ks = 0; ks < 2; ++ks) {
            const float* xp = x + (size_t)row_a * 64 + ks * 32 + quad * 8;
            float4 x0 = ((const float4*)xp)[0];
            float4 x1 = ((const float4*)xp)[1];
            float xf[8] = {x0.x, x0.y, x0.z, x0.w, x1.x, x1.y, x1.z, x1.w};
            bf16x8 h8, l8;
            #pragma unroll
            for (int j = 0; j < 8; ++j) {
                __bf16 hi = (__bf16)xf[j];
                h8[j] = hi;
                l8[j] = (__bf16)(xf[j] - (float)hi);
            }
            ah[ks] = h8;
            al[ks] = l8;
        }
        f32x4 acc[4];
        #pragma unroll
        for (int ct = 0; ct < 4; ++ct) {
            f32x4 a = {0.f, 0.f, 0.f, 0.f};
            a = __builtin_amdgcn_mfma_f32_16x16x32_bf16(ah[0], bh[ct*2+0], a, 0, 0, 0);
            a = __builtin_amdgcn_mfma_f32_16x16x32_bf16(ah[1], bh[ct*2+1], a, 0, 0, 0);
            a = __builtin_amdgcn_mfma_f32_16x16x32_bf16(ah[0], bl[ct*2+0], a, 0, 0, 0);
            a = __builtin_amdgcn_mfma_f32_16x16x32_bf16(ah[1], bl[ct*2+1], a, 0, 0, 0);
            a = __builtin_amdgcn_mfma_f32_16x16x32_bf16(al[0], bh[ct*2+0], a, 0, 0, 0);
            a = __builtin_amdgcn_mfma_f32_16x16x32_bf16(al[1], bh[ct*2+1], a, 0, 0, 0);
            acc[ct] = a;
        }
        #pragma unroll
        for (int ct = 0; ct < 4; ++ct) {
            #pragma unroll
            for (int reg = 0; reg < 4; ++reg) {
                int r = rt * 16 + quad * 4 + reg;
                hs[r * 256 + (ct * 16 + l15) * 4 + w] = f2bf(acc[ct][reg]);
            }
        }
        #pragma unroll
        for (int reg = 0; reg < 4; ++reg) {
            float ps = 0.f, pd = 0.f;
            #pragma unroll
            for (int ct = 0; ct < 4; ++ct) {
                ps += acc[ct][reg] * att_s[ct];
                pd += acc[ct][reg] * att_d[ct];
            }
            #pragma unroll
            for (int off = 1; off < 16; off <<= 1) {
                ps += __shfl_xor(ps, off);
                pd += __shfl_xor(pd, off);
            }
            int row = row0 + rt * 16 + quad * 4 + reg;
            if (l15 == 0 && row < N_NODES) {
                a_src[row * 4 + w] = ps;
                a_dst[row * 4 + w] = pd;
            }
        }
    }
    __syncthreads();
    const uint4* ls = (const uint4*)hs;
    uint4* gd = (uint4*)h_bf;
    #pragma unroll
    for (int i = 0; i < 8; ++i) {
        int g = i * 256 + t;
        int rl = g >> 5;                       // 32 uint4 per row
        if (row0 + rl < N_NODES)
            gd[(size_t)row0 * 32 + g] = ls[g];
    }
}

// ---------------------------------------------------------------------------
// K3a: histogram of dst (cnt pre-zeroed)
__global__ __launch_bounds__(256) void k_hist(const int* __restrict__ ei,
                                              int* __restrict__ counts) {
    int e = blockIdx.x * 256 + threadIdx.x;
    if (e < N_EDGES) atomicAdd(&counts[ei[N_EDGES + e]], 1);
}

// K3b: single-block (1024 thr = 16 waves) coalesced scan: cnt -> rowptr, cursor.
__global__ __launch_bounds__(1024) void k_scan(const int* __restrict__ cnt,
                                               int* __restrict__ rowptr,
                                               int* __restrict__ cursor) {
    __shared__ int wsum[16];
    int t = threadIdx.x, lane = t & 63, w = t >> 6;
    const int WR = (N_NODES + 15) / 16;        // 3125 per wave
    int begin = w * WR;
    int end = begin + WR; if (end > N_NODES) end = N_NODES;
    // phase 1: region sums (coalesced stride-64)
    int s = 0;
    for (int i = begin + lane; i < end; i += 64) s += cnt[i];
    #pragma unroll
    for (int off = 32; off >= 1; off >>= 1) s += __shfl_xor(s, off);
    if (lane == 0) wsum[w] = s;
    __syncthreads();
    if (t < 16) {
        int orig = wsum[t];
        int v = orig;
        #pragma unroll
        for (int off = 1; off < 16; off <<= 1) {
            int u = __shfl_up(v, off);
            if (t >= off) v += u;
        }
        wsum[t] = v - orig;                    // exclusive wave base
    }
    __syncthreads();
    // phase 2: windowed coalesced wave-scan
    int run = wsum[w];
    int nwin = (end - begin + 63) / 64;
    for (int win = 0; win < nwin; ++win) {
        int i = begin + win * 64 + lane;
        int c = (i < end) ? cnt[i] : 0;
        int v = c;
        #pragma unroll
        for (int off = 1; off < 64; off <<= 1) {
            int u = __shfl_up(v, off);
            if (lane >= off) v += u;
        }
        int excl = run + v - c;
        if (i < end) { rowptr[i] = excl; cursor[i] = excl; }
        run += __shfl(v, 63);
    }
    if (t == 0) rowptr[N_NODES] = N_EDGES;
}

// ---------------------------------------------------------------------------
// K4: streaming edge pass. 4 edges/wave/iter, float4 loads. Writes raw ae4
// in EDGE order (coalesced) + 4B eid scatter into dst-sorted slot. No sumae.
__global__ __launch_bounds__(256) void k_edge(const int* __restrict__ ei,
                                              const float* __restrict__ edge_attr,
                                              const float* __restrict__ v_t,
                                              int* __restrict__ cursor,
                                              float4* __restrict__ edge_ae,
                                              int* __restrict__ sorted_eid) {
    int t = threadIdx.x;
    int lane = t & 63;
    int sub = lane & 15;                    // 16 lanes per edge
    int eq = lane >> 4;                     // edge index within quad
    float4 v0 = ((const float4*)(v_t +   0))[sub];
    float4 v1 = ((const float4*)(v_t +  64))[sub];
    float4 v2 = ((const float4*)(v_t + 128))[sub];
    float4 v3 = ((const float4*)(v_t + 192))[sub];
    int wave_id = blockIdx.x * 4 + (t >> 6);
    int nwaves = gridDim.x * 4;
    const float4* ea4 = (const float4*)edge_attr;
    for (int g = wave_id; g < N_EDGES / 4; g += nwaves) {
        int e = g * 4 + eq;
        float4 ea = ea4[(size_t)e * 16 + sub];
        float p0 = ea.x * v0.x + ea.y * v0.y + ea.z * v0.z + ea.w * v0.w;
        float p1 = ea.x * v1.x + ea.y * v1.y + ea.z * v1.z + ea.w * v1.w;
        float p2 = ea.x * v2.x + ea.y * v2.y + ea.z * v2.z + ea.w * v2.w;
        float p3 = ea.x * v3.x + ea.y * v3.y + ea.z * v3.z + ea.w * v3.w;
        #pragma unroll
        for (int off = 1; off < 16; off <<= 1) {
            p0 += __shfl_xor(p0, off);
            p1 += __shfl_xor(p1, off);
            p2 += __shfl_xor(p2, off);
            p3 += __shfl_xor(p3, off);
        }
        if (sub == 0) {
            int dst = ei[N_EDGES + e];
            int p = atomicAdd(&cursor[dst], 1);
            sorted_eid[p] = e;
            edge_ae[e] = make_float4(p0, p1, p2, p3);
        }
    }
}

// ---------------------------------------------------------------------------
// K5: one wave per node. Lane-parallel preload (eid -> ae,src -> a_src[src],
// exp) with per-lane z / sumae accumulation; shfl-broadcast h-gather loop;
// final 64-lane reduce; self-loop fused; out written once. No atomics.
__global__ __launch_bounds__(256) void k_gather(const int* __restrict__ rowptr,
                                                const int* __restrict__ sorted_eid,
                                                const float4* __restrict__ edge_ae,
                                                const int* __restrict__ ei,
                                                const unsigned short* __restrict__ h_bf,
                                                const float* __restrict__ a_src,
                                                const float* __restrict__ a_dst,
                                                const float* __restrict__ bias,
                                                float* __restrict__ out) {
    int wave = (int)((blockIdx.x * 256u + threadIdx.x) >> 6);
    int lane = threadIdx.x & 63;
    if (wave >= N_NODES) return;
    int n = wave;
    int r0 = rowptr[n];
    int r1 = rowptr[n + 1];
    float4 ad = ((const float4*)a_dst)[n];
    const uint2* h2 = (const uint2*)h_bf;       // h2[n*64 + c] = 4 bf16 heads
    float a0 = 0.f, a1 = 0.f, a2 = 0.f, a3 = 0.f;
    float z0 = 0.f, z1 = 0.f, z2 = 0.f, z3 = 0.f;
    float s0 = 0.f, s1 = 0.f, s2 = 0.f, s3 = 0.f;
    for (int base = r0; base < r1; base += 64) {
        int cnt = r1 - base; if (cnt > 64) cnt = 64;
        int idx = base + (lane < cnt ? lane : 0);
        int eid = sorted_eid[idx];              // coalesced
        float4 ae = edge_ae[eid];               // lane-parallel random 16B
        int msrc = ei[eid];                     // lane-parallel random 4B
        float4 asv = ((const float4*)a_src)[msrc];
        float l0 = ae.x + asv.x + ad.x, l1 = ae.y + asv.y + ad.y;
        float l2 = ae.z + asv.z + ad.z, l3 = ae.w + asv.w + ad.w;
        l0 = fmaxf(l0, SLOPE * l0); l1 = fmaxf(l1, SLOPE * l1);
        l2 = fmaxf(l2, SLOPE * l2); l3 = fmaxf(l3, SLOPE * l3);
        float mw0 = __expf(l0), mw1 = __expf(l1);
        float mw2 = __expf(l2), mw3 = __expf(l3);
        if (lane < cnt) {
            z0 += mw0; z1 += mw1; z2 += mw2; z3 += mw3;
            s0 += ae.x; s1 += ae.y; s2 += ae.z; s3 += ae.w;
        }
        #pragma unroll 8
        for (int j = 0; j < cnt; ++j) {
            int src = __shfl(msrc, j);
            float e0 = __shfl(mw0, j), e1 = __shfl(mw1, j);
            float e2 = __shfl(mw2, j), e3 = __shfl(mw3, j);
            uint2 hv = h2[(size_t)src * 64 + lane];   // coalesced 512B/wave
            float h0 = __uint_as_float(hv.x << 16);
            float h1 = __uint_as_float(hv.x & 0xffff0000u);
            float h2f = __uint_as_float(hv.y << 16);
            float h3 = __uint_as_float(hv.y & 0xffff0000u);
            a0 += h0 * e0; a1 += h1 * e1; a2 += h2f * e2; a3 += h3 * e3;
        }
    }
    // reduce z / sumae across the wave
    #pragma unroll
    for (int off = 32; off >= 1; off >>= 1) {
        z0 += __shfl_xor(z0, off); z1 += __shfl_xor(z1, off);
        z2 += __shfl_xor(z2, off); z3 += __shfl_xor(z3, off);
        s0 += __shfl_xor(s0, off); s1 += __shfl_xor(s1, off);
        s2 += __shfl_xor(s2, off); s3 += __shfl_xor(s3, off);
    }
    // self loop: a_edge_self = sumae / max(deg,1)
    float d = (float)(r1 - r0); if (d < 1.f) d = 1.f;
    float rdeg = 1.f / d;
    float4 la = ((const float4*)a_src)[n];
    float l0 = la.x + ad.x + s0 * rdeg;
    float l1 = la.y + ad.y + s1 * rdeg;
    float l2 = la.z + ad.z + s2 * rdeg;
    float l3 = la.w + ad.w + s3 * rdeg;
    l0 = fmaxf(l0, SLOPE * l0); l1 = fmaxf(l1, SLOPE * l1);
    l2 = fmaxf(l2, SLOPE * l2); l3 = fmaxf(l3, SLOPE * l3);
    float w0 = __expf(l0), w1 = __expf(l1), w2 = __expf(l2), w3 = __expf(l3);
    uint2 hv = h2[(size_t)n * 64 + lane];
    float h0 = __uint_as_float(hv.x << 16);
    float h1 = __uint_as_float(hv.x & 0xffff0000u);
    float h2f = __uint_as_float(hv.y << 16);
    float h3 = __uint_as_float(hv.y & 0xffff0000u);
    a0 += h0 * w0; z0 += w0;
    a1 += h1 * w1; z1 += w1;
    a2 += h2f * w2; z2 += w2;
    a3 += h3 * w3; z3 += w3;
    size_t ob = (size_t)n * HC + lane;
    out[ob]       = a0 / (z0 + 1e-16f) + bias[lane];
    out[ob + 64]  = a1 / (z1 + 1e-16f) + bias[64 + lane];
    out[ob + 128] = a2 / (z2 + 1e-16f) + bias[128 + lane];
    out[ob + 192] = a3 / (z3 + 1e-16f) + bias[192 + lane];
}

// ---------------------------------------------------------------------------
extern "C" void kernel_launch(void* const* d_in, const int* in_sizes, int n_in,
                              void* d_out, int out_size, void* d_ws, size_t ws_size,
                              hipStream_t stream) {
    const float* x        = (const float*)d_in[0];
    const int*   ei       = (const int*)d_in[1];   // (2,E) int32
    const float* edge_attr= (const float*)d_in[2];
    const float* W        = (const float*)d_in[3];
    const float* W_e      = (const float*)d_in[4];
    const float* att_src  = (const float*)d_in[5];
    const float* att_dst  = (const float*)d_in[6];
    const float* att_edge = (const float*)d_in[7];
    const float* bias     = (const float*)d_in[8];
    float* out = (float*)d_out;

    // workspace layout
    unsigned short* h_bf  = (unsigned short*)d_ws;             // N*256 bf16 = 25.6 MB
    float*  a_src     = (float*)(h_bf + (size_t)N_NODES * 256);// N*4
    float*  a_dst     = a_src + N_NODES * 4;                   // N*4
    float*  v_t       = a_dst + N_NODES * 4;                   // 256
    float4* edge_ae   = (float4*)(v_t + 256);                  // E float4 (12.8 MB)
    int*    sorted_eid= (int*)(edge_ae + N_EDGES);             // E
    int*    rowptr    = sorted_eid + N_EDGES;                  // N+1
    int*    cursor    = rowptr + N_NODES + 1;                  // N
    int*    cnt       = cursor + N_NODES;                      // N (zeroed)

    hipMemsetAsync(cnt, 0, (size_t)N_NODES * sizeof(int), stream);

    k_vedge<<<1, 256, 0, stream>>>(W_e, att_edge, v_t);
    k_proj<<<(N_NODES + 63) / 64, 256, 0, stream>>>(x, W, att_src, att_dst,
                                                    h_bf, a_src, a_dst);
    k_hist<<<(N_EDGES + 255) / 256, 256, 0, stream>>>(ei, cnt);
    k_scan<<<1, 1024, 0, stream>>>(cnt, rowptr, cursor);
    k_edge<<<2048, 256, 0, stream>>>(ei, edge_attr, v_t, cursor,
                                     edge_ae, sorted_eid);
    k_gather<<<(N_NODES + 3) / 4, 256, 0, stream>>>(rowptr, sorted_eid, edge_ae,
                                                    ei, h_bf, a_src, a_dst,
                                                    bias, out);
}